// Round 5
// baseline (392.512 us; speedup 1.0000x reference)
//
#include <hip/hip_runtime.h>
#include <stdint.h>

// Pipeline: cast->bf16 | rope table | QKV GEMM (bf16 MFMA) | rope+layout |
//           V-transpose | flash attention | out-proj GEMM (f32 out)
// B=2 T=2048 D_MODEL=2048 H=32 KVH=8 HD=64

typedef unsigned short u16;
typedef __attribute__((ext_vector_type(8))) short short8;
typedef __attribute__((ext_vector_type(4))) float floatx4;

#define T_SEQ 2048
#define DMODEL 2048
#define NHEADS 32
#define KVHEADS 8
#define HDIM 64

__device__ __forceinline__ u16 f2bf(float f) {
  uint32_t u = __builtin_bit_cast(uint32_t, f);
  u = (u + 0x7FFFu + ((u >> 16) & 1u)) >> 16;
  return (u16)u;
}
__device__ __forceinline__ float bf2f(u16 h) {
  uint32_t u = ((uint32_t)h) << 16;
  return __builtin_bit_cast(float, u);
}

__device__ __forceinline__ void gld_lds16(const void* g, void* l) {
  __builtin_amdgcn_global_load_lds(
      (const __attribute__((address_space(1))) unsigned int*)g,
      (__attribute__((address_space(3))) unsigned int*)l, 16, 0, 0);
}

// ---------------- f32 -> bf16 cast (x4 vectorized) ----------------
__global__ __launch_bounds__(256) void cvt_kernel(const float* __restrict__ src,
                                                  u16* __restrict__ dst, int n4) {
  int i = blockIdx.x * 256 + threadIdx.x;
  if (i >= n4) return;
  float4 v = ((const float4*)src)[i];
  ushort4 o;
  o.x = f2bf(v.x); o.y = f2bf(v.y); o.z = f2bf(v.z); o.w = f2bf(v.w);
  ((ushort4*)dst)[i] = o;
}

// ---------------- rope table: cos/sin [T][32] ----------------
__global__ __launch_bounds__(256) void rope_table_kernel(float* __restrict__ cosT,
                                                         float* __restrict__ sinT) {
  int idx = blockIdx.x * 256 + threadIdx.x;  // 65536 = 2048*32
  int t = idx >> 5, i = idx & 31;
  float invf = 1.0f / powf(10000.0f, (float)i / 32.0f);
  float a = (float)t * invf;
  cosT[idx] = cosf(a);
  sinT[idx] = sinf(a);
}

// ---------------- bf16 GEMM, A[M,K] * B[N,K]^T -> C[M,N] ----------------
// 128x128 tile, BK=64, 4 waves (2x2), global_load_lds w/ pre-swizzled source,
// XOR-swizzled ds_read_b128 (slot ^= row&7 within 128B rows).
template <bool OUT_F32>
__global__ __launch_bounds__(256) void gemm_bt(const u16* __restrict__ A,
                                               const u16* __restrict__ Bm,
                                               float* __restrict__ Cf,
                                               u16* __restrict__ Cb,
                                               int M, int N, int K) {
  __shared__ u16 As[128 * 64];
  __shared__ u16 Bs[128 * 64];
  const int tid = threadIdx.x;
  const int lane = tid & 63;
  const int wid = tid >> 6;
  const int wr = wid >> 1, wc = wid & 1;
  const long bm = (long)blockIdx.y * 128;
  const long bn = (long)blockIdx.x * 128;

  floatx4 acc[4][4] = {};

  for (int kt = 0; kt < K; kt += 64) {
#pragma unroll
    for (int c = 0; c < 4; ++c) {
      int g = (wid * 4 + c) * 64 + lane;      // 16B granule index, 1024 total
      int row = g >> 3, slot = g & 7;
      int ss = slot ^ (row & 7);              // inverse-swizzle the SOURCE
      gld_lds16(A + (bm + row) * (long)K + kt + ss * 8, (char*)As + g * 16);
      gld_lds16(Bm + (bn + row) * (long)K + kt + ss * 8, (char*)Bs + g * 16);
    }
    __syncthreads();
#pragma unroll
    for (int ks = 0; ks < 2; ++ks) {
      short8 af[4], bfr[4];
#pragma unroll
      for (int m = 0; m < 4; ++m) {
        int row = wr * 64 + m * 16 + (lane & 15);
        int slot = (ks * 4 + (lane >> 4)) ^ (row & 7);
        af[m] = *(const short8*)((const char*)As + row * 128 + slot * 16);
      }
#pragma unroll
      for (int n = 0; n < 4; ++n) {
        int row = wc * 64 + n * 16 + (lane & 15);
        int slot = (ks * 4 + (lane >> 4)) ^ (row & 7);
        bfr[n] = *(const short8*)((const char*)Bs + row * 128 + slot * 16);
      }
#pragma unroll
      for (int m = 0; m < 4; ++m)
#pragma unroll
        for (int n = 0; n < 4; ++n)
          acc[m][n] = __builtin_amdgcn_mfma_f32_16x16x32_bf16(af[m], bfr[n],
                                                              acc[m][n], 0, 0, 0);
    }
    __syncthreads();
  }
#pragma unroll
  for (int m = 0; m < 4; ++m)
#pragma unroll
    for (int n = 0; n < 4; ++n)
#pragma unroll
      for (int r = 0; r < 4; ++r) {
        long row = bm + wr * 64 + m * 16 + (lane >> 4) * 4 + r;
        long col = bn + wc * 64 + n * 16 + (lane & 15);
        if constexpr (OUT_F32)
          Cf[row * N + col] = acc[m][n][r];
        else
          Cb[row * N + col] = f2bf(acc[m][n][r]);
      }
}

// ---------------- RoPE + head layout for Q,K ----------------
// QKV[4096][3072] (cols: Q 0..2047, K 2048..2559, V 2560..3071)
__global__ __launch_bounds__(256) void rope_apply_kernel(
    const u16* __restrict__ QKV, const float* __restrict__ cosT,
    const float* __restrict__ sinT, u16* __restrict__ Qh, u16* __restrict__ Kh) {
  int idx = blockIdx.x * 256 + threadIdx.x;  // B*T*2560
  int c = idx % 2560;
  int bt = idx / 2560;
  int t = bt & (T_SEQ - 1);
  int b = bt >> 11;
  int hd = c & 63;
  int i = hd & 31;
  float cs = cosT[t * 32 + i];
  float sn = sinT[t * 32 + i];
  long base = (long)bt * 3072;
  float xv = bf2f(QKV[base + c]);
  int pairc = (hd < 32) ? c + 32 : c - 32;
  float xp = bf2f(QKV[base + pairc]);
  float rot = (hd < 32) ? -xp : xp;
  float ov = xv * cs + rot * sn;
  if (c < 2048) {
    int h = c >> 6;
    Qh[((long)(b * NHEADS + h) * T_SEQ + t) * HDIM + hd] = f2bf(ov);
  } else {
    int kv = (c - 2048) >> 6;
    Kh[((long)(b * KVHEADS + kv) * T_SEQ + t) * HDIM + hd] = f2bf(ov);
  }
}

// ---------------- V transpose: QKV V-cols -> Vt[B][KVH][D][T] ----------------
__global__ __launch_bounds__(256) void v_transpose_kernel(const u16* __restrict__ QKV,
                                                          u16* __restrict__ Vt) {
  __shared__ u16 tl[64 * 65];
  int blk = blockIdx.x;  // 512 = B*KVH*(T/64)
  int ttile = blk & 31;
  int kvh = (blk >> 5) & 7;
  int b = blk >> 8;
  int tid = threadIdx.x;
  long bt0 = (long)b * T_SEQ + ttile * 64;
#pragma unroll
  for (int j = 0; j < 2; ++j) {
    int chunk = tid * 2 + j;
    int el = chunk * 8;
    int row = el >> 6, col = el & 63;
    short8 v = *(const short8*)(QKV + (bt0 + row) * 3072 + 2560 + kvh * 64 + col);
#pragma unroll
    for (int k = 0; k < 8; ++k) tl[(col + k) * 65 + row] = (u16)v[k];
  }
  __syncthreads();
#pragma unroll
  for (int j = 0; j < 2; ++j) {
    int chunk = tid * 2 + j;
    int el = chunk * 8;
    int d = el >> 6, t0 = el & 63;
    short8 o;
#pragma unroll
    for (int k = 0; k < 8; ++k) o[k] = (short)tl[d * 65 + t0 + k];
    *(short8*)(Vt + ((long)(b * KVHEADS + kvh) * HDIM + d) * T_SEQ + ttile * 64 + t0) = o;
  }
}

// ---------------- causal GQA flash attention ----------------
// Block: 4 waves, 64 q-rows (16/wave). K/V tiles 64x64 in LDS (swizzled).
// S^T = mfma(K, Q) so q is the lane column -> wave-parallel softmax via shfl_xor.
__global__ __launch_bounds__(256) void attn_kernel(const u16* __restrict__ Qh,
                                                   const u16* __restrict__ Kh,
                                                   const u16* __restrict__ Vt,
                                                   u16* __restrict__ O) {
  __shared__ u16 Ks[64 * 64];
  __shared__ u16 Vs[64 * 64];
  __shared__ u16 Ps[4 * 1024];  // per-wave P tile [16 q][64 t]
  const int tid = threadIdx.x;
  const int lane = tid & 63;
  const int w = tid >> 6;
  const int blk = blockIdx.x;
  const int qb = blk & 31;
  const int h = (blk >> 5) & 31;
  const int b = blk >> 10;
  const int kvh = h >> 2;
  const int qbase = qb * 64;
  const int l15 = lane & 15;
  const int l4 = lane >> 4;

  const u16* Qp = Qh + ((long)(b * NHEADS + h) * T_SEQ + qbase + w * 16 + l15) * HDIM;
  short8 qf0 = *(const short8*)(Qp + l4 * 8);
  short8 qf1 = *(const short8*)(Qp + 32 + l4 * 8);
  const u16* Kbase = Kh + (long)(b * KVHEADS + kvh) * T_SEQ * HDIM;
  const u16* Vbase = Vt + (long)(b * KVHEADS + kvh) * HDIM * T_SEQ;

  float m_run = -1e30f, l_run = 0.f;
  floatx4 oA[4] = {};
  const int qg = qbase + w * 16 + l15;  // this lane's q row (stats owner)
  char* Pw = (char*)Ps + w * 2048;

  for (int kt = 0; kt <= qb; ++kt) {
#pragma unroll
    for (int c = 0; c < 2; ++c) {
      int g = (w * 2 + c) * 64 + lane;  // 512 granules per 8KB tile
      int row = g >> 3, slot = g & 7;
      int ss = slot ^ (row & 7);
      gld_lds16(Kbase + (long)(kt * 64 + row) * HDIM + ss * 8, (char*)Ks + g * 16);
      gld_lds16(Vbase + (long)row * T_SEQ + kt * 64 + ss * 8, (char*)Vs + g * 16);
    }
    __syncthreads();

    // S^T[t][q] = sum_d K[t][d] Q[q][d]
    floatx4 st[4] = {};
#pragma unroll
    for (int ks = 0; ks < 2; ++ks) {
      short8 qf = ks ? qf1 : qf0;
#pragma unroll
      for (int tt = 0; tt < 4; ++tt) {
        int row = tt * 16 + l15;
        int slot = (ks * 4 + l4) ^ (row & 7);
        short8 kf = *(const short8*)((const char*)Ks + row * 128 + slot * 16);
        st[tt] = __builtin_amdgcn_mfma_f32_16x16x32_bf16(kf, qf, st[tt], 0, 0, 0);
      }
    }

    // scale + causal mask + online softmax (q = lane&15; t in regs)
    float p[4][4];
    float mt = -1e30f;
#pragma unroll
    for (int tt = 0; tt < 4; ++tt)
#pragma unroll
      for (int r = 0; r < 4; ++r) {
        int tg = kt * 64 + tt * 16 + l4 * 4 + r;
        float v = st[tt][r] * 0.125f;
        v = (tg <= qg) ? v : -1e30f;
        p[tt][r] = v;
        mt = fmaxf(mt, v);
      }
    mt = fmaxf(mt, __shfl_xor(mt, 16));
    mt = fmaxf(mt, __shfl_xor(mt, 32));
    float m_new = fmaxf(m_run, mt);
    float alpha = __expf(m_run - m_new);
    float lsum = 0.f;
#pragma unroll
    for (int tt = 0; tt < 4; ++tt)
#pragma unroll
      for (int r = 0; r < 4; ++r) {
        float e = __expf(p[tt][r] - m_new);
        p[tt][r] = e;
        lsum += e;
      }
    lsum += __shfl_xor(lsum, 16);
    lsum += __shfl_xor(lsum, 32);
    l_run = l_run * alpha + lsum;
    m_run = m_new;

    // P (bf16) -> per-wave LDS, swizzled rows of 128B
#pragma unroll
    for (int tt = 0; tt < 4; ++tt) {
      uint2 pk;
      pk.x = (uint32_t)f2bf(p[tt][0]) | ((uint32_t)f2bf(p[tt][1]) << 16);
      pk.y = (uint32_t)f2bf(p[tt][2]) | ((uint32_t)f2bf(p[tt][3]) << 16);
      int t0 = tt * 16 + l4 * 4;
      int slot = (t0 >> 3) ^ (l15 & 7);
      int half = (t0 & 4) ? 8 : 0;
      *(uint2*)(Pw + l15 * 128 + slot * 16 + half) = pk;
    }
    asm volatile("s_waitcnt lgkmcnt(0)" ::: "memory");

    // O rescale by alpha(q of my acc rows)
    float a0 = __shfl(alpha, l4 * 4 + 0);
    float a1 = __shfl(alpha, l4 * 4 + 1);
    float a2 = __shfl(alpha, l4 * 4 + 2);
    float a3 = __shfl(alpha, l4 * 4 + 3);
#pragma unroll
    for (int dd = 0; dd < 4; ++dd) {
      oA[dd][0] *= a0; oA[dd][1] *= a1; oA[dd][2] *= a2; oA[dd][3] *= a3;
    }
    // O[q][d] += P[q][t] V[t][d]
#pragma unroll
    for (int ks2 = 0; ks2 < 2; ++ks2) {
      int slotp = (ks2 * 4 + l4) ^ (l15 & 7);
      short8 pa = *(const short8*)(Pw + l15 * 128 + slotp * 16);
#pragma unroll
      for (int dd = 0; dd < 4; ++dd) {
        int row = dd * 16 + l15;
        int slot = (ks2 * 4 + l4) ^ (row & 7);
        short8 vb = *(const short8*)((const char*)Vs + row * 128 + slot * 16);
        oA[dd] = __builtin_amdgcn_mfma_f32_16x16x32_bf16(pa, vb, oA[dd], 0, 0, 0);
      }
    }
    __syncthreads();
  }

  float linv = 1.0f / l_run;
  float i0 = __shfl(linv, l4 * 4 + 0);
  float i1 = __shfl(linv, l4 * 4 + 1);
  float i2 = __shfl(linv, l4 * 4 + 2);
  float i3 = __shfl(linv, l4 * 4 + 3);
  float iv[4] = {i0, i1, i2, i3};
#pragma unroll
  for (int dd = 0; dd < 4; ++dd)
#pragma unroll
    for (int r = 0; r < 4; ++r) {
      int trow = qbase + w * 16 + l4 * 4 + r;
      int col = h * 64 + dd * 16 + l15;
      O[((long)b * T_SEQ + trow) * DMODEL + col] = f2bf(oA[dd][r] * iv[r]);
    }
}

extern "C" void kernel_launch(void* const* d_in, const int* in_sizes, int n_in,
                              void* d_out, int out_size, void* d_ws, size_t ws_size,
                              hipStream_t stream) {
  const float* x = (const float*)d_in[0];
  const float* Wq = (const float*)d_in[1];
  const float* Wk = (const float*)d_in[2];
  const float* Wv = (const float*)d_in[3];
  const float* Wo = (const float*)d_in[4];
  float* out = (float*)d_out;

  // ws layout (bytes); Obuf aliases x_bf (dead after GEMM1). Total 88,604,672 B.
  char* ws = (char*)d_ws;
  u16* x_bf = (u16*)(ws);                    // 16,777,216
  u16* Obuf = (u16*)(ws);                    // alias
  u16* Wqkv_bf = (u16*)(ws + 16777216);      // 12,582,912
  u16* Wo_bf = (u16*)(ws + 29360128);        //  8,388,608
  u16* QKV = (u16*)(ws + 37748736);          // 25,165,824
  u16* Qh = (u16*)(ws + 62914560);           // 16,777,216
  u16* Kh = (u16*)(ws + 79691776);           //  4,194,304
  u16* Vt = (u16*)(ws + 83886080);           //  4,194,304
  float* cosT = (float*)(ws + 88080384);     //    262,144
  float* sinT = (float*)(ws + 88342528);     //    262,144

  // casts
  cvt_kernel<<<8192, 256, 0, stream>>>(x, x_bf, 2097152);
  cvt_kernel<<<4096, 256, 0, stream>>>(Wq, Wqkv_bf, 1048576);
  cvt_kernel<<<1024, 256, 0, stream>>>(Wk, Wqkv_bf + 2048 * 2048, 262144);
  cvt_kernel<<<1024, 256, 0, stream>>>(Wv, Wqkv_bf + 2560 * 2048, 262144);
  cvt_kernel<<<4096, 256, 0, stream>>>(Wo, Wo_bf, 1048576);
  rope_table_kernel<<<256, 256, 0, stream>>>(cosT, sinT);

  // QKV projection: [4096,2048] x [3072,2048]^T -> [4096,3072] bf16
  dim3 g1(24, 32);
  gemm_bt<false><<<g1, 256, 0, stream>>>(x_bf, Wqkv_bf, nullptr, QKV, 4096, 3072, 2048);

  rope_apply_kernel<<<40960, 256, 0, stream>>>(QKV, cosT, sinT, Qh, Kh);
  v_transpose_kernel<<<512, 256, 0, stream>>>(QKV, Vt);

  attn_kernel<<<2048, 256, 0, stream>>>(Qh, Kh, Vt, Obuf);

  // out projection: [4096,2048] x [2048,2048]^T -> f32 d_out
  dim3 g2(16, 32);
  gemm_bt<true><<<g2, 256, 0, stream>>>(Obuf, Wo_bf, out, nullptr, 4096, 2048, 2048);
}

// Round 6
// 376.809 us; speedup vs baseline: 1.0417x; 1.0417x over previous
//
#include <hip/hip_runtime.h>
#include <stdint.h>

// Pipeline: cast->bf16 | rope table | QKV GEMM (bf16 MFMA) | rope+layout |
//           V-transpose | flash attention (2-phase dbuf) | out-proj GEMM
// B=2 T=2048 D_MODEL=2048 H=32 KVH=8 HD=64

typedef unsigned short u16;
typedef __attribute__((ext_vector_type(8))) short short8;
typedef __attribute__((ext_vector_type(4))) float floatx4;

#define T_SEQ 2048
#define DMODEL 2048
#define NHEADS 32
#define KVHEADS 8
#define HDIM 64

__device__ __forceinline__ u16 f2bf(float f) {
  uint32_t u = __builtin_bit_cast(uint32_t, f);
  u = (u + 0x7FFFu + ((u >> 16) & 1u)) >> 16;
  return (u16)u;
}
__device__ __forceinline__ float bf2f(u16 h) {
  uint32_t u = ((uint32_t)h) << 16;
  return __builtin_bit_cast(float, u);
}

__device__ __forceinline__ void gld_lds16(const void* g, void* l) {
  __builtin_amdgcn_global_load_lds(
      (const __attribute__((address_space(1))) unsigned int*)g,
      (__attribute__((address_space(3))) unsigned int*)l, 16, 0, 0);
}

// ---------------- f32 -> bf16 cast (x4 vectorized) ----------------
__global__ __launch_bounds__(256) void cvt_kernel(const float* __restrict__ src,
                                                  u16* __restrict__ dst, int n4) {
  int i = blockIdx.x * 256 + threadIdx.x;
  if (i >= n4) return;
  float4 v = ((const float4*)src)[i];
  ushort4 o;
  o.x = f2bf(v.x); o.y = f2bf(v.y); o.z = f2bf(v.z); o.w = f2bf(v.w);
  ((ushort4*)dst)[i] = o;
}

// ---------------- rope table: cos/sin [T][32] ----------------
__global__ __launch_bounds__(256) void rope_table_kernel(float* __restrict__ cosT,
                                                         float* __restrict__ sinT) {
  int idx = blockIdx.x * 256 + threadIdx.x;  // 65536 = 2048*32
  int t = idx >> 5, i = idx & 31;
  float invf = 1.0f / powf(10000.0f, (float)i / 32.0f);
  float a = (float)t * invf;
  cosT[idx] = cosf(a);
  sinT[idx] = sinf(a);
}

// ---------------- bf16 GEMM, A[M,K] * B[N,K]^T -> C[M,N] ----------------
template <bool OUT_F32>
__global__ __launch_bounds__(256) void gemm_bt(const u16* __restrict__ A,
                                               const u16* __restrict__ Bm,
                                               float* __restrict__ Cf,
                                               u16* __restrict__ Cb,
                                               int M, int N, int K) {
  __shared__ u16 As[128 * 64];
  __shared__ u16 Bs[128 * 64];
  const int tid = threadIdx.x;
  const int lane = tid & 63;
  const int wid = tid >> 6;
  const int wr = wid >> 1, wc = wid & 1;
  const long bm = (long)blockIdx.y * 128;
  const long bn = (long)blockIdx.x * 128;

  floatx4 acc[4][4] = {};

  for (int kt = 0; kt < K; kt += 64) {
#pragma unroll
    for (int c = 0; c < 4; ++c) {
      int g = (wid * 4 + c) * 64 + lane;      // 16B granule index, 1024 total
      int row = g >> 3, slot = g & 7;
      int ss = slot ^ (row & 7);              // inverse-swizzle the SOURCE
      gld_lds16(A + (bm + row) * (long)K + kt + ss * 8, (char*)As + g * 16);
      gld_lds16(Bm + (bn + row) * (long)K + kt + ss * 8, (char*)Bs + g * 16);
    }
    __syncthreads();
#pragma unroll
    for (int ks = 0; ks < 2; ++ks) {
      short8 af[4], bfr[4];
#pragma unroll
      for (int m = 0; m < 4; ++m) {
        int row = wr * 64 + m * 16 + (lane & 15);
        int slot = (ks * 4 + (lane >> 4)) ^ (row & 7);
        af[m] = *(const short8*)((const char*)As + row * 128 + slot * 16);
      }
#pragma unroll
      for (int n = 0; n < 4; ++n) {
        int row = wc * 64 + n * 16 + (lane & 15);
        int slot = (ks * 4 + (lane >> 4)) ^ (row & 7);
        bfr[n] = *(const short8*)((const char*)Bs + row * 128 + slot * 16);
      }
#pragma unroll
      for (int m = 0; m < 4; ++m)
#pragma unroll
        for (int n = 0; n < 4; ++n)
          acc[m][n] = __builtin_amdgcn_mfma_f32_16x16x32_bf16(af[m], bfr[n],
                                                              acc[m][n], 0, 0, 0);
    }
    __syncthreads();
  }
#pragma unroll
  for (int m = 0; m < 4; ++m)
#pragma unroll
    for (int n = 0; n < 4; ++n)
#pragma unroll
      for (int r = 0; r < 4; ++r) {
        long row = bm + wr * 64 + m * 16 + (lane >> 4) * 4 + r;
        long col = bn + wc * 64 + n * 16 + (lane & 15);
        if constexpr (OUT_F32)
          Cf[row * N + col] = acc[m][n][r];
        else
          Cb[row * N + col] = f2bf(acc[m][n][r]);
      }
}

// ---------------- RoPE + head layout for Q,K ----------------
__global__ __launch_bounds__(256) void rope_apply_kernel(
    const u16* __restrict__ QKV, const float* __restrict__ cosT,
    const float* __restrict__ sinT, u16* __restrict__ Qh, u16* __restrict__ Kh) {
  int idx = blockIdx.x * 256 + threadIdx.x;  // B*T*2560
  int c = idx % 2560;
  int bt = idx / 2560;
  int t = bt & (T_SEQ - 1);
  int b = bt >> 11;
  int hd = c & 63;
  int i = hd & 31;
  float cs = cosT[t * 32 + i];
  float sn = sinT[t * 32 + i];
  long base = (long)bt * 3072;
  float xv = bf2f(QKV[base + c]);
  int pairc = (hd < 32) ? c + 32 : c - 32;
  float xp = bf2f(QKV[base + pairc]);
  float rot = (hd < 32) ? -xp : xp;
  float ov = xv * cs + rot * sn;
  if (c < 2048) {
    int h = c >> 6;
    Qh[((long)(b * NHEADS + h) * T_SEQ + t) * HDIM + hd] = f2bf(ov);
  } else {
    int kv = (c - 2048) >> 6;
    Kh[((long)(b * KVHEADS + kv) * T_SEQ + t) * HDIM + hd] = f2bf(ov);
  }
}

// ---------------- V transpose: QKV V-cols -> Vt[B][KVH][D][T] ----------------
__global__ __launch_bounds__(256) void v_transpose_kernel(const u16* __restrict__ QKV,
                                                          u16* __restrict__ Vt) {
  __shared__ u16 tl[64 * 65];
  int blk = blockIdx.x;  // 512 = B*KVH*(T/64)
  int ttile = blk & 31;
  int kvh = (blk >> 5) & 7;
  int b = blk >> 8;
  int tid = threadIdx.x;
  long bt0 = (long)b * T_SEQ + ttile * 64;
#pragma unroll
  for (int j = 0; j < 2; ++j) {
    int chunk = tid * 2 + j;
    int el = chunk * 8;
    int row = el >> 6, col = el & 63;
    short8 v = *(const short8*)(QKV + (bt0 + row) * 3072 + 2560 + kvh * 64 + col);
#pragma unroll
    for (int k = 0; k < 8; ++k) tl[(col + k) * 65 + row] = (u16)v[k];
  }
  __syncthreads();
#pragma unroll
  for (int j = 0; j < 2; ++j) {
    int chunk = tid * 2 + j;
    int el = chunk * 8;
    int d = el >> 6, t0 = el & 63;
    short8 o;
#pragma unroll
    for (int k = 0; k < 8; ++k) o[k] = (short)tl[d * 65 + t0 + k];
    *(short8*)(Vt + ((long)(b * KVHEADS + kvh) * HDIM + d) * T_SEQ + ttile * 64 + t0) = o;
  }
}

// ---------------- causal GQA flash attention (2-phase dbuf pipeline) ----------
// 4 waves, 64 q-rows. K/V double-buffered 64x64 LDS tiles; STAGE(kt+1) issued
// before compute(kt); one vmcnt(0)+s_barrier per iter (T3 minimal 2-phase).
// T13 defer-max, T5 setprio, diagonal-only masking, heavy-first qb order.
__global__ __launch_bounds__(256) void attn_kernel(const u16* __restrict__ Qh,
                                                   const u16* __restrict__ Kh,
                                                   const u16* __restrict__ Vt,
                                                   u16* __restrict__ O) {
  __shared__ u16 Ks[2][64 * 64];
  __shared__ u16 Vs[2][64 * 64];
  __shared__ u16 Ps[4 * 1024];  // per-wave P tile [16 q][64 t]
  const int tid = threadIdx.x;
  const int lane = tid & 63;
  const int w = tid >> 6;
  const int blk = blockIdx.x;
  const int qb = 31 - (blk & 31);  // heavy blocks first (LPT)
  const int h = (blk >> 5) & 31;
  const int b = blk >> 10;
  const int kvh = h >> 2;
  const int qbase = qb * 64;
  const int l15 = lane & 15;
  const int l4 = lane >> 4;

  const u16* Qp = Qh + ((long)(b * NHEADS + h) * T_SEQ + qbase + w * 16 + l15) * HDIM;
  short8 qf0 = *(const short8*)(Qp + l4 * 8);
  short8 qf1 = *(const short8*)(Qp + 32 + l4 * 8);
  const u16* Kbase = Kh + (long)(b * KVHEADS + kvh) * T_SEQ * HDIM;
  const u16* Vbase = Vt + (long)(b * KVHEADS + kvh) * HDIM * T_SEQ;

  float m_run = -1e30f, l_run = 0.f;
  floatx4 oA[4] = {};
  const int qg = qbase + w * 16 + l15;  // this lane's q row (stats owner)
  char* Pw = (char*)Ps + w * 2048;

  auto STAGE = [&](int kt, int buf) {
#pragma unroll
    for (int c = 0; c < 2; ++c) {
      int g = (w * 2 + c) * 64 + lane;  // 512 granules per 8KB tile
      int row = g >> 3, slot = g & 7;
      int ss = slot ^ (row & 7);
      gld_lds16(Kbase + (long)(kt * 64 + row) * HDIM + ss * 8,
                (char*)Ks[buf] + g * 16);
      gld_lds16(Vbase + (long)row * T_SEQ + kt * 64 + ss * 8,
                (char*)Vs[buf] + g * 16);
    }
  };

  // prologue: stage tile 0
  STAGE(0, 0);
  asm volatile("s_waitcnt vmcnt(0)" ::: "memory");
  __builtin_amdgcn_s_barrier();
  asm volatile("" ::: "memory");

  for (int kt = 0; kt <= qb; ++kt) {
    const int cur = kt & 1;
    if (kt < qb) STAGE(kt + 1, cur ^ 1);  // prefetch next tile (other buffer)

    const char* Kc = (const char*)Ks[cur];
    const char* Vc = (const char*)Vs[cur];

    // S^T[t][q] = sum_d K[t][d] Q[q][d]
    floatx4 st[4] = {};
    __builtin_amdgcn_s_setprio(1);
#pragma unroll
    for (int ks = 0; ks < 2; ++ks) {
      short8 qf = ks ? qf1 : qf0;
#pragma unroll
      for (int tt = 0; tt < 4; ++tt) {
        int row = tt * 16 + l15;
        int slot = (ks * 4 + l4) ^ (row & 7);
        short8 kf = *(const short8*)(Kc + row * 128 + slot * 16);
        st[tt] = __builtin_amdgcn_mfma_f32_16x16x32_bf16(kf, qf, st[tt], 0, 0, 0);
      }
    }
    __builtin_amdgcn_s_setprio(0);

    // scale + (diagonal-only) causal mask + tile max
    float p[4][4];
    float mt = -1e30f;
    if (kt == qb) {
#pragma unroll
      for (int tt = 0; tt < 4; ++tt)
#pragma unroll
        for (int r = 0; r < 4; ++r) {
          int tg = kt * 64 + tt * 16 + l4 * 4 + r;
          float v = st[tt][r] * 0.125f;
          v = (tg <= qg) ? v : -1e30f;
          p[tt][r] = v;
          mt = fmaxf(mt, v);
        }
    } else {
#pragma unroll
      for (int tt = 0; tt < 4; ++tt)
#pragma unroll
        for (int r = 0; r < 4; ++r) {
          float v = st[tt][r] * 0.125f;
          p[tt][r] = v;
          mt = fmaxf(mt, v);
        }
    }
    mt = fmaxf(mt, __shfl_xor(mt, 16));
    mt = fmaxf(mt, __shfl_xor(mt, 32));

    // T13 defer-max: skip rescale when tile max doesn't exceed m_run+8
    bool defer = __all(mt - m_run <= 8.0f);
    float m_use, alpha;
    if (defer) {
      m_use = m_run;
      alpha = 1.0f;
    } else {
      m_use = fmaxf(m_run, mt);
      alpha = __expf(m_run - m_use);
    }
    float lsum = 0.f;
#pragma unroll
    for (int tt = 0; tt < 4; ++tt)
#pragma unroll
      for (int r = 0; r < 4; ++r) {
        float e = __expf(p[tt][r] - m_use);
        p[tt][r] = e;
        lsum += e;
      }
    lsum += __shfl_xor(lsum, 16);
    lsum += __shfl_xor(lsum, 32);
    l_run = l_run * alpha + lsum;
    m_run = m_use;

    // P (bf16) -> per-wave LDS, swizzled rows of 128B
#pragma unroll
    for (int tt = 0; tt < 4; ++tt) {
      uint2 pk;
      pk.x = (uint32_t)f2bf(p[tt][0]) | ((uint32_t)f2bf(p[tt][1]) << 16);
      pk.y = (uint32_t)f2bf(p[tt][2]) | ((uint32_t)f2bf(p[tt][3]) << 16);
      int t0 = tt * 16 + l4 * 4;
      int slot = (t0 >> 3) ^ (l15 & 7);
      int half = (t0 & 4) ? 8 : 0;
      *(uint2*)(Pw + l15 * 128 + slot * 16 + half) = pk;
    }
    asm volatile("s_waitcnt lgkmcnt(0)" ::: "memory");

    // O rescale by alpha(q of my acc rows) — only when max advanced
    if (!defer) {
      float a0 = __shfl(alpha, l4 * 4 + 0);
      float a1 = __shfl(alpha, l4 * 4 + 1);
      float a2 = __shfl(alpha, l4 * 4 + 2);
      float a3 = __shfl(alpha, l4 * 4 + 3);
#pragma unroll
      for (int dd = 0; dd < 4; ++dd) {
        oA[dd][0] *= a0; oA[dd][1] *= a1; oA[dd][2] *= a2; oA[dd][3] *= a3;
      }
    }
    // O[q][d] += P[q][t] V[t][d]
    __builtin_amdgcn_s_setprio(1);
#pragma unroll
    for (int ks2 = 0; ks2 < 2; ++ks2) {
      int slotp = (ks2 * 4 + l4) ^ (l15 & 7);
      short8 pa = *(const short8*)(Pw + l15 * 128 + slotp * 16);
#pragma unroll
      for (int dd = 0; dd < 4; ++dd) {
        int row = dd * 16 + l15;
        int slot = (ks2 * 4 + l4) ^ (row & 7);
        short8 vb = *(const short8*)(Vc + row * 128 + slot * 16);
        oA[dd] = __builtin_amdgcn_mfma_f32_16x16x32_bf16(pa, vb, oA[dd], 0, 0, 0);
      }
    }
    __builtin_amdgcn_s_setprio(0);

    // end of tile: next-tile loads landed; all reads of buf[cur] done
    asm volatile("s_waitcnt vmcnt(0)" ::: "memory");
    __builtin_amdgcn_s_barrier();
    asm volatile("" ::: "memory");
  }

  float linv = 1.0f / l_run;
  float i0 = __shfl(linv, l4 * 4 + 0);
  float i1 = __shfl(linv, l4 * 4 + 1);
  float i2 = __shfl(linv, l4 * 4 + 2);
  float i3 = __shfl(linv, l4 * 4 + 3);
  float iv[4] = {i0, i1, i2, i3};
#pragma unroll
  for (int dd = 0; dd < 4; ++dd)
#pragma unroll
    for (int r = 0; r < 4; ++r) {
      int trow = qbase + w * 16 + l4 * 4 + r;
      int col = h * 64 + dd * 16 + l15;
      O[((long)b * T_SEQ + trow) * DMODEL + col] = f2bf(oA[dd][r] * iv[r]);
    }
}

extern "C" void kernel_launch(void* const* d_in, const int* in_sizes, int n_in,
                              void* d_out, int out_size, void* d_ws, size_t ws_size,
                              hipStream_t stream) {
  const float* x = (const float*)d_in[0];
  const float* Wq = (const float*)d_in[1];
  const float* Wk = (const float*)d_in[2];
  const float* Wv = (const float*)d_in[3];
  const float* Wo = (const float*)d_in[4];
  float* out = (float*)d_out;

  // ws layout (bytes); Obuf aliases x_bf (dead after GEMM1). Total 88,604,672 B.
  char* ws = (char*)d_ws;
  u16* x_bf = (u16*)(ws);                    // 16,777,216
  u16* Obuf = (u16*)(ws);                    // alias
  u16* Wqkv_bf = (u16*)(ws + 16777216);      // 12,582,912
  u16* Wo_bf = (u16*)(ws + 29360128);        //  8,388,608
  u16* QKV = (u16*)(ws + 37748736);          // 25,165,824
  u16* Qh = (u16*)(ws + 62914560);           // 16,777,216
  u16* Kh = (u16*)(ws + 79691776);           //  4,194,304
  u16* Vt = (u16*)(ws + 83886080);           //  4,194,304
  float* cosT = (float*)(ws + 88080384);     //    262,144
  float* sinT = (float*)(ws + 88342528);     //    262,144

  // casts
  cvt_kernel<<<8192, 256, 0, stream>>>(x, x_bf, 2097152);
  cvt_kernel<<<4096, 256, 0, stream>>>(Wq, Wqkv_bf, 1048576);
  cvt_kernel<<<1024, 256, 0, stream>>>(Wk, Wqkv_bf + 2048 * 2048, 262144);
  cvt_kernel<<<1024, 256, 0, stream>>>(Wv, Wqkv_bf + 2560 * 2048, 262144);
  cvt_kernel<<<4096, 256, 0, stream>>>(Wo, Wo_bf, 1048576);
  rope_table_kernel<<<256, 256, 0, stream>>>(cosT, sinT);

  // QKV projection: [4096,2048] x [3072,2048]^T -> [4096,3072] bf16
  dim3 g1(24, 32);
  gemm_bt<false><<<g1, 256, 0, stream>>>(x_bf, Wqkv_bf, nullptr, QKV, 4096, 3072, 2048);

  rope_apply_kernel<<<40960, 256, 0, stream>>>(QKV, cosT, sinT, Qh, Kh);
  v_transpose_kernel<<<512, 256, 0, stream>>>(QKV, Vt);

  attn_kernel<<<2048, 256, 0, stream>>>(Qh, Kh, Vt, Obuf);

  // out projection: [4096,2048] x [2048,2048]^T -> f32 d_out
  dim3 g2(16, 32);
  gemm_bt<true><<<g2, 256, 0, stream>>>(Obuf, Wo_bf, out, nullptr, 4096, 2048, 2048);
}